// Round 5
// baseline (607.726 us; speedup 1.0000x reference)
//
#include <hip/hip_runtime.h>
#include <hip/hip_bf16.h>

typedef __attribute__((ext_vector_type(8))) short bf16x8;
typedef __attribute__((ext_vector_type(4))) float f32x4;
typedef __hip_bfloat16 bf16;

#define S_LEN 2048
#define HIDDEN 4096
#define NH 32
#define NKV 8
#define DH 128
#define ROTD 64
#define QKVW 6144              // fused QKV row width (32*128 + 8*128 + 8*128)
#define KOFF 4096              // K column offset in fused buffer
#define VOFF 5120              // V column offset
#define ATT_SCALE 0.08838834764831845f
#define RMS_EPS 1e-6f
#define VPITCH 72              // Ps row pitch: 144B = 9*16 -> aligned, 2-way banks

#define BAR() __builtin_amdgcn_s_barrier()
#define VMCNT(n) asm volatile("s_waitcnt vmcnt(" #n ")" ::: "memory")
#define LGKM(n)  asm volatile("s_waitcnt lgkmcnt(" #n ")" ::: "memory")

static __device__ __forceinline__ unsigned short f2bu(float f) {
    bf16 h = __float2bfloat16(f);
    return __builtin_bit_cast(unsigned short, h);
}

static __device__ __forceinline__ void load_lds_16(const bf16* g, bf16* l) {
    __builtin_amdgcn_global_load_lds((const __attribute__((address_space(1))) void*)g,
                                     (__attribute__((address_space(3))) void*)l, 16, 0, 0);
}

// ---------------- fp32 -> bf16 cast (vectorized float4) ----------------
__global__ __launch_bounds__(256) void cast_f32_bf16(const float* __restrict__ src,
                                                     unsigned short* __restrict__ dst, int n4) {
    int i = blockIdx.x * 256 + threadIdx.x;
    if (i >= n4) return;
    float4 v = reinterpret_cast<const float4*>(src)[i];
    ushort4 o;
    o.x = f2bu(v.x); o.y = f2bu(v.y); o.z = f2bu(v.z); o.w = f2bu(v.w);
    reinterpret_cast<ushort4*>(dst)[i] = o;
}

// ---------------- fp32 in-place add (split-K reduction) ----------------
__global__ __launch_bounds__(256) void add_f32(float* __restrict__ dst,
                                               const float* __restrict__ src, int n4) {
    int i = blockIdx.x * 256 + threadIdx.x;
    if (i >= n4) return;
    float4 a = reinterpret_cast<float4*>(dst)[i];
    float4 b = reinterpret_cast<const float4*>(src)[i];
    a.x += b.x; a.y += b.y; a.z += b.z; a.w += b.w;
    reinterpret_cast<float4*>(dst)[i] = a;
}

// ---------------- C[M,N] = A[M,K] @ B[N,K]^T ----------------
// 256x256 tile, BK=64, 8 waves (2M x 4N), 8-phase schedule (T2+T3+T4+T5).
// Unchanged from round 4 (verified: 0 bank conflicts, no spill, 133 us @ QKV).
// NOTE (round-2 lesson): do NOT add extra register fragment sets; acc(128)+av/bv(64)
// is at the VGPR budget for 2 waves/EU — more sets spill to scratch.
#define LDA_SUB(bufi, half) do {                                                        \
    const bf16* _ab = &As[bufi][half][0];                                               \
    _Pragma("unroll") for (int mf = 0; mf < 4; ++mf) {                                  \
        const int _r = arow + mf * 16;                                                  \
        _Pragma("unroll") for (int kk = 0; kk < 2; ++kk)                                \
            av[mf][kk] = *reinterpret_cast<const bf16x8*>(                              \
                _ab + (((_r << 6) + kk * 32 + quad * 8) ^ xorv));                       \
    } } while (0)

#define LDB_SUB(bufi, half, set) do {                                                   \
    const bf16* _bb = &Bs[bufi][half][0];                                               \
    _Pragma("unroll") for (int nf = 0; nf < 2; ++nf) {                                  \
        const int _r = brow + nf * 16;                                                  \
        _Pragma("unroll") for (int kk = 0; kk < 2; ++kk)                                \
            bv[set][nf][kk] = *reinterpret_cast<const bf16x8*>(                         \
                _bb + (((_r << 6) + kk * 32 + quad * 8) ^ xorv));                       \
    } } while (0)

#define MMQ(mh, nh, set) do {                                                           \
    _Pragma("unroll") for (int mf = 0; mf < 4; ++mf)                                    \
    _Pragma("unroll") for (int nf = 0; nf < 2; ++nf)                                    \
    _Pragma("unroll") for (int kk = 0; kk < 2; ++kk)                                    \
        acc[mh][nh][mf][nf] = __builtin_amdgcn_mfma_f32_16x16x32_bf16(                  \
            av[mf][kk], bv[set][nf][kk], acc[mh][nh][mf][nf], 0, 0, 0);                 \
    } while (0)

#define STAGE_A(bufi, half, tau) do {                                                   \
    const bf16* _s = Abase + (size_t)(half) * 128 * K + (size_t)(tau) * 64;             \
    load_lds_16(_s + sro0, &As[bufi][half][e0]);                                        \
    load_lds_16(_s + sro1, &As[bufi][half][e1]); } while (0)

#define STAGE_B(bufi, half, tau) do {                                                   \
    const bf16* _s = Bbase + (size_t)(half) * 128 * K + (size_t)(tau) * 64;             \
    load_lds_16(_s + sro0, &Bs[bufi][half][e0]);                                        \
    load_lds_16(_s + sro1, &Bs[bufi][half][e1]); } while (0)

template <typename OutT>
__global__ __launch_bounds__(512, 2) void gemm256(const bf16* __restrict__ A,
                                                  const bf16* __restrict__ B,
                                                  OutT* __restrict__ C,
                                                  OutT* __restrict__ C2,
                                                  int M, int N, int K, int ktiles) {
    __shared__ bf16 As[2][2][128 * 64];
    __shared__ bf16 Bs[2][2][128 * 64];

    const int tid  = threadIdx.x;
    const int lane = tid & 63;
    const int lq   = lane & 15;
    const int quad = lane >> 4;
    const int wave = tid >> 6;
    const int wr   = wave >> 2;      // 0..1 (M)
    const int wc   = wave & 3;       // 0..3 (N)

    // XCD-aware block swizzle (grid.x here is a multiple of 8)
    const int nwg = gridDim.x;
    const int cpx = nwg >> 3;
    const int wg  = (blockIdx.x & 7) * cpx + (blockIdx.x >> 3);
    const int ntn = N >> 8;
    const int m0  = (wg / ntn) << 8;
    const int n0  = (wg % ntn) << 8;
    const int ksl = blockIdx.y;      // K-slice index (split-K)

    const int NT = ktiles;           // 64-wide K tiles this slice (even, >= 4)

    // ---- staging thread-constants: dest byte d -> pre-swizzled source offset o
    const int d0 = tid * 16;
    const int d1 = 8192 + tid * 16;
    const int o0 = d0 ^ (((d0 >> 7) & 7) << 4);
    const int o1 = d1 ^ (((d1 >> 7) & 7) << 4);
    const int e0 = d0 >> 1;          // LDS dest element offset (linear)
    const int e1 = d1 >> 1;
    const size_t sro0 = (size_t)((o0 >> 1) >> 6) * K + ((o0 >> 1) & 63);
    const size_t sro1 = (size_t)((o1 >> 1) >> 6) * K + ((o1 >> 1) & 63);
    const bf16* Abase = A + (size_t)m0 * K + (size_t)ksl * ktiles * 64;
    const bf16* Bbase = B + (size_t)n0 * K + (size_t)ksl * ktiles * 64;
    OutT* __restrict__ Cw = ksl ? C2 : C;

    // ---- fragment read constants
    const int arow = wr * 64 + lq;   // + mf*16  (row within A half)
    const int brow = wc * 32 + lq;   // + nf*16  (row within B half)
    const int xorv = (lq & 7) << 3;  // element-offset swizzle ((row&7)<<4 bytes)

    f32x4  acc[2][2][4][2] = {};
    bf16x8 av[4][2];                 // A-subtile for current mh
    bf16x8 bv[2][2][2];              // B-subtiles for nh=0 and nh=1 (both kept live)

    // ---- prologue: stage 7 half-tiles in sigma order, drain tile 0
    STAGE_B(0, 0, 0); STAGE_A(0, 0, 0); STAGE_B(0, 1, 0); STAGE_A(0, 1, 0);
    STAGE_B(1, 0, 1); STAGE_A(1, 0, 1); STAGE_B(1, 1, 1);
    VMCNT(6);
    BAR();

    for (int t = 0; t < NT; ++t) {
        const int buf = t & 1;

        // ---- p0: quadrant (0,0)
        LDA_SUB(buf, 0);
        LDB_SUB(buf, 0, 0);
        if (t + 1 < NT) STAGE_A(buf ^ 1, 1, t + 1);
        LGKM(8);
        BAR();
        LGKM(0);
        __builtin_amdgcn_s_setprio(1);
        MMQ(0, 0, 0);
        __builtin_amdgcn_s_setprio(0);
        BAR();

        // ---- p1: quadrant (0,1)
        LDB_SUB(buf, 1, 1);
        if (t + 2 < NT) STAGE_B(buf, 0, t + 2);
        BAR();
        LGKM(0);
        __builtin_amdgcn_s_setprio(1);
        MMQ(0, 1, 1);
        __builtin_amdgcn_s_setprio(0);
        BAR();

        // ---- p2: quadrant (1,1)
        LDA_SUB(buf, 1);
        if (t + 2 < NT) STAGE_A(buf, 0, t + 2);
        BAR();
        LGKM(0);
        __builtin_amdgcn_s_setprio(1);
        MMQ(1, 1, 1);
        __builtin_amdgcn_s_setprio(0);
        BAR();

        // ---- p3: quadrant (1,0)  (A from p2, B set 0 from p0 -- registers only)
        if (t + 2 < NT) STAGE_B(buf, 1, t + 2);
        BAR();
        __builtin_amdgcn_s_setprio(1);
        MMQ(1, 0, 0);
        __builtin_amdgcn_s_setprio(0);
        if (t < NT - 2) { VMCNT(6); } else { VMCNT(0); }   // boundary: next tile resident
        BAR();
    }

    // ---- epilogue: C-write (C/D layout: col = lane&15, row = quad*4 + r)
#pragma unroll
    for (int mh = 0; mh < 2; ++mh)
#pragma unroll
        for (int nh = 0; nh < 2; ++nh)
#pragma unroll
            for (int mf = 0; mf < 4; ++mf)
#pragma unroll
                for (int nf = 0; nf < 2; ++nf)
#pragma unroll
                    for (int r = 0; r < 4; ++r) {
                        const int row = m0 + mh * 128 + wr * 64 + mf * 16 + quad * 4 + r;
                        const int col = n0 + nh * 128 + wc * 32 + nf * 16 + lq;
                        const float v = acc[mh][nh][mf][nf][r];
                        const size_t idx = (size_t)row * N + col;
                        if constexpr (sizeof(OutT) == 2) Cw[idx] = __float2bfloat16(v);
                        else                             Cw[idx] = v;
                    }
}

// ---------------- fused RMSNorm + partial RoPE (in place, strided) ----------------
__global__ __launch_bounds__(256) void norm_rope(bf16* __restrict__ buf,
                                                 const float* __restrict__ w,
                                                 const float* __restrict__ cosp,
                                                 const float* __restrict__ sinp,
                                                 int log2nh, int stride, int coloff) {
    const int lane = threadIdx.x & 63;
    const int wave = threadIdx.x >> 6;
    const int row  = blockIdx.x * 4 + wave;
    const int s    = row >> log2nh;
    const int hh   = row & ((1 << log2nh) - 1);
    bf16* p = buf + (size_t)s * stride + coloff + hh * DH;

    float x1 = __bfloat162float(p[lane]);
    float x2 = __bfloat162float(p[64 + lane]);

    float ss = x1 * x1 + x2 * x2;
#pragma unroll
    for (int off = 1; off < 64; off <<= 1) ss += __shfl_xor(ss, off);
    float rs = rsqrtf(ss * (1.0f / 128.0f) + RMS_EPS);

    float y1 = x1 * rs * w[lane];
    float y2 = x2 * rs * w[64 + lane];

    float partner = __shfl_xor(y1, 32);
    float c  = cosp[(size_t)s * ROTD + lane];
    float sn = sinp[(size_t)s * ROTD + lane];
    float rot = (lane < 32) ? (y1 * c - partner * sn) : (y1 * c + partner * sn);

    p[lane]      = __float2bfloat16(rot);
    p[64 + lane] = __float2bfloat16(y2);
}

// ---------------- V transpose: qkv V cols -> vt(NKV*DH, S) ----------------
__global__ __launch_bounds__(256) void transpose_v(const bf16* __restrict__ v,
                                                   bf16* __restrict__ vt,
                                                   int stride, int colofs) {
    __shared__ bf16 t[32][65];
    const int c0 = blockIdx.x * 32;
    const int s0 = blockIdx.y * 64;
    {
        const int j  = threadIdx.x & 31;
        const int i0 = threadIdx.x >> 5;
#pragma unroll
        for (int p = 0; p < 8; ++p) {
            int si = p * 8 + i0;
            t[j][si] = v[(size_t)(s0 + si) * stride + colofs + c0 + j];
        }
    }
    __syncthreads();
    {
        const int ii = threadIdx.x & 63;
        const int j0 = threadIdx.x >> 6;
#pragma unroll
        for (int p = 0; p < 8; ++p) {
            int c = p * 4 + j0;
            vt[(size_t)(c0 + c) * S_LEN + s0 + ii] = t[c][ii];
        }
    }
}

// ---------------- block-cooperative MFMA flash attention (causal, GQA) ----------------
// 8 waves / 512 threads: waves 0-3 process EVEN k-tiles, waves 4-7 ODD k-tiles
// (private online-softmax partials, merged at the end). Halves the per-wave serial
// chain length. K staged via global_load_lds with XOR swizzle (byte ^= (row&7)<<4,
// linear dest + pre-swizzled source, matching read). V read directly from global
// (L2-resident: 512 KB/head shared by 16 blocks) -- no V staging.
// LDS 50 KB -> 2 blocks/CU -> 4 waves/SIMD (2x the previous TLP).
struct FlashSmem {
    bf16 Ks[2][64][128];     // [parity][key][dh], rows XOR-swizzled
    bf16 Ps[8][16][VPITCH];  // per-wave P round-trip
};

static __device__ __forceinline__ void attn_qblock(int q0, int n_iter, int h, int kvh,
                                                   const bf16* __restrict__ QKV,
                                                   const bf16* __restrict__ VT,
                                                   bf16* __restrict__ O,
                                                   FlashSmem* sm) {
    const int tid  = threadIdx.x;
    const int lane = tid & 63;
    const int wave = tid >> 6;       // 0..7
    const int wq   = wave & 3;       // q-subtile within the 64 rows
    const int g    = wave >> 2;      // k-tile parity group
    const int lq   = lane & 15;
    const int quad = lane >> 4;
    const int qr0  = q0 + wq * 16;

    // Q fragments (A-layout), softmax scale folded
    bf16x8 qf[4];
    const bf16* qrow = QKV + (size_t)(qr0 + lq) * QKVW + h * DH + quad * 8;
#pragma unroll
    for (int i = 0; i < 4; ++i) {
        bf16x8 qv = *reinterpret_cast<const bf16x8*>(qrow + 32 * i);
#pragma unroll
        for (int j = 0; j < 8; ++j) {
            bf16 bb = __builtin_bit_cast(bf16, (unsigned short)qv[j]);
            qv[j] = (short)__builtin_bit_cast(unsigned short,
                        __float2bfloat16(__bfloat162float(bb) * ATT_SCALE));
        }
        qf[i] = qv;
    }

    f32x4 o[8];
#pragma unroll
    for (int t2 = 0; t2 < 8; ++t2) o[t2] = (f32x4){0.f, 0.f, 0.f, 0.f};
    float m_i[4], l_i[4];
#pragma unroll
    for (int r = 0; r < 4; ++r) { m_i[r] = -1e30f; l_i[r] = 0.f; }

    // K staging constants: dest byte d (linear) -> pre-swizzled source col
    const int d0 = tid * 16;                      // rows 0..31 of a tile
    const int d1 = 8192 + tid * 16;               // rows 32..63
    const int r0 = d0 >> 8;
    const int r1 = d1 >> 8;
    const int c0 = ((d0 ^ ((r0 & 7) << 4)) & 255) >> 1;
    const int c1 = ((d1 ^ ((r1 & 7) << 4)) & 255) >> 1;
    const bf16* Kg = QKV + (size_t)KOFF + kvh * DH;
    const size_t so0 = (size_t)r0 * QKVW + c0;
    const size_t so1 = (size_t)r1 * QKVW + c1;
    bf16* ksb = &sm->Ks[0][0][0];
    bf16* pb  = &sm->Ps[wave][0][0];
    const bf16* vb = VT + (size_t)(kvh * DH + lq) * S_LEN + quad * 8;

    const int nrounds = (n_iter + 1) >> 1;
    for (int rr = 0; rr < nrounds; ++rr) {
        const int kt0 = 2 * rr;
        // ---- stage both parity tiles (uniform guards; all 512 threads)
        {
            const bf16* s0 = Kg + (size_t)kt0 * 64 * QKVW;
            load_lds_16(s0 + so0, ksb + (d0 >> 1));
            load_lds_16(s0 + so1, ksb + (d1 >> 1));
            if (kt0 + 1 < n_iter) {
                const bf16* s1 = s0 + (size_t)64 * QKVW;
                load_lds_16(s1 + so0, ksb + 8192 + (d0 >> 1));
                load_lds_16(s1 + so1, ksb + 8192 + (d1 >> 1));
            }
        }
        VMCNT(0);
        BAR();

        const int ktg = kt0 + g;
        if (ktg < n_iter) {
            const int k0 = ktg * 64;
            const char* ksg = (const char*)(ksb + g * 8192);

            // QK^T on this group's staged tile (swizzled ds_read)
            float p[4][4];
#pragma unroll
            for (int t = 0; t < 4; ++t) {
                f32x4 sacc = (f32x4){0.f, 0.f, 0.f, 0.f};
#pragma unroll
                for (int i = 0; i < 4; ++i) {
                    const int krow = t * 16 + lq;
                    const int kb = (krow << 8) + ((quad * 8 + 32 * i) << 1);
                    bf16x8 kf = *reinterpret_cast<const bf16x8*>(ksg + (kb ^ ((krow & 7) << 4)));
                    sacc = __builtin_amdgcn_mfma_f32_16x16x32_bf16(qf[i], kf, sacc, 0, 0, 0);
                }
#pragma unroll
                for (int r = 0; r < 4; ++r) {
                    int qi = qr0 + quad * 4 + r;
                    int ki = k0 + t * 16 + lq;
                    p[t][r] = (ki > qi) ? -1e30f : sacc[r];
                }
            }

            float rowmax[4];
#pragma unroll
            for (int r = 0; r < 4; ++r)
                rowmax[r] = fmaxf(fmaxf(p[0][r], p[1][r]), fmaxf(p[2][r], p[3][r]));
#pragma unroll
            for (int off = 1; off < 16; off <<= 1)
#pragma unroll
                for (int r = 0; r < 4; ++r) rowmax[r] = fmaxf(rowmax[r], __shfl_xor(rowmax[r], off));

            float alpha[4];
#pragma unroll
            for (int r = 0; r < 4; ++r) {
                float mn = fmaxf(m_i[r], rowmax[r]);
                alpha[r] = __expf(m_i[r] - mn);
                m_i[r] = mn;
            }
#pragma unroll
            for (int t = 0; t < 4; ++t)
#pragma unroll
                for (int r = 0; r < 4; ++r) p[t][r] = __expf(p[t][r] - m_i[r]);

            float rsum[4];
#pragma unroll
            for (int r = 0; r < 4; ++r) rsum[r] = (p[0][r] + p[1][r]) + (p[2][r] + p[3][r]);
#pragma unroll
            for (int off = 1; off < 16; off <<= 1)
#pragma unroll
                for (int r = 0; r < 4; ++r) rsum[r] += __shfl_xor(rsum[r], off);
#pragma unroll
            for (int r = 0; r < 4; ++r) l_i[r] = l_i[r] * alpha[r] + rsum[r];

            // P (C-layout) -> per-wave LDS -> A-layout
#pragma unroll
            for (int t = 0; t < 4; ++t)
#pragma unroll
                for (int r = 0; r < 4; ++r)
                    pb[(quad * 4 + r) * VPITCH + t * 16 + lq] = __float2bfloat16(p[t][r]);
            __threadfence_block();

#pragma unroll
            for (int t2 = 0; t2 < 8; ++t2)
#pragma unroll
                for (int r = 0; r < 4; ++r) o[t2][r] *= alpha[r];

            // PV: P from LDS, V fragments straight from global (L2-resident)
#pragma unroll
            for (int hh = 0; hh < 2; ++hh) {
                bf16x8 pa = *reinterpret_cast<const bf16x8*>(pb + lq * VPITCH + hh * 32 + quad * 8);
#pragma unroll
                for (int t2 = 0; t2 < 8; ++t2) {
                    bf16x8 vf = *reinterpret_cast<const bf16x8*>(
                        vb + (size_t)(t2 * 16) * S_LEN + k0 + hh * 32);
                    o[t2] = __builtin_amdgcn_mfma_f32_16x16x32_bf16(pa, vf, o[t2], 0, 0, 0);
                }
            }
        }
        BAR();   // protect Ks before next round's staging
    }

    // ---- cross-group combine (scratch reuses Ks as f32; all prior reads drained)
    float* osc = (float*)&sm->Ks[0][0][0];                 // 4 waves * 64 lanes * 32 f32 = 32KB
    float* mlc = (float*)&sm->Ps[0][0][0];                 // 4 waves * 64 lanes * 8 f32
    if (g == 1) {
        const int wl = (wave - 4) * 64 + lane;
#pragma unroll
        for (int t2 = 0; t2 < 8; ++t2)
            *reinterpret_cast<f32x4*>(osc + wl * 32 + t2 * 4) = o[t2];
#pragma unroll
        for (int r = 0; r < 4; ++r) { mlc[wl * 8 + r] = m_i[r]; mlc[wl * 8 + 4 + r] = l_i[r]; }
    }
    BAR();
    if (g == 0) {
        const int wl = wave * 64 + lane;
        float sa[4], sb[4];
#pragma unroll
        for (int r = 0; r < 4; ++r) {
            float mb = mlc[wl * 8 + r];
            float lb = mlc[wl * 8 + 4 + r];
            float mm = fmaxf(m_i[r], mb);
            float ea = __expf(m_i[r] - mm);
            float eb = __expf(mb - mm);
            float inv = 1.0f / (l_i[r] * ea + lb * eb);
            sa[r] = ea * inv;
            sb[r] = eb * inv;
        }
#pragma unroll
        for (int t2 = 0; t2 < 8; ++t2) {
            f32x4 ob = *reinterpret_cast<const f32x4*>(osc + wl * 32 + t2 * 4);
#pragma unroll
            for (int r = 0; r < 4; ++r)
                O[(size_t)(qr0 + quad * 4 + r) * (NH * DH) + h * DH + t2 * 16 + lq] =
                    __float2bfloat16(o[t2][r] * sa[r] + ob[r] * sb[r]);
        }
    }
}

__global__ __launch_bounds__(512, 4) void flash_attn(const bf16* __restrict__ QKV,
                                                     const bf16* __restrict__ VT,
                                                     bf16* __restrict__ O) {
    __shared__ FlashSmem sm;
    const int b  = blockIdx.x;       // 0..511
    const int h  = b & 31;
    const int pr = b >> 5;           // 0..15
    const int kvh = h >> 2;
    // heavy q-block first, then its light complement: uniform 33 tiles total
    attn_qblock((31 - pr) * 64, 32 - pr, h, kvh, QKV, VT, O, &sm);
    __syncthreads();
    attn_qblock(pr * 64,        pr + 1,  h, kvh, QKV, VT, O, &sm);
}

extern "C" void kernel_launch(void* const* d_in, const int* in_sizes, int n_in,
                              void* d_out, int out_size, void* d_ws, size_t ws_size,
                              hipStream_t stream) {
    const float* hs   = (const float*)d_in[0];
    const float* cosp = (const float*)d_in[1];
    const float* sinp = (const float*)d_in[2];
    const float* Wq   = (const float*)d_in[3];
    const float* Wk   = (const float*)d_in[4];
    const float* Wv   = (const float*)d_in[5];
    const float* Wo   = (const float*)d_in[6];
    const float* qw   = (const float*)d_in[7];
    const float* kw   = (const float*)d_in[8];
    float* out = (float*)d_out;

    char* ws = (char*)d_ws;
    size_t off = 0;
    auto carve = [&](size_t bytes) { char* p = ws + off; off += (bytes + 255) & ~(size_t)255; return p; };

    bf16* hsb  = (bf16*)carve((size_t)S_LEN * HIDDEN * 2);          // hidden bf16; reused as AO
    bf16* wqkv = (bf16*)carve((size_t)QKVW * HIDDEN * 2);           // fused [6144, 4096]; reused as split-K partial
    bf16* wob  = (bf16*)carve((size_t)HIDDEN * NH * DH * 2);
    bf16* qkv  = (bf16*)carve((size_t)S_LEN * QKVW * 2);            // [S, 6144]
    bf16* vtb  = (bf16*)carve((size_t)NKV * DH * S_LEN * 2);

    // 1. casts
    cast_f32_bf16<<<(S_LEN * HIDDEN / 4 + 255) / 256, 256, 0, stream>>>(hs, (unsigned short*)hsb, S_LEN * HIDDEN / 4);
    cast_f32_bf16<<<(NH * DH * HIDDEN / 4 + 255) / 256, 256, 0, stream>>>(Wq, (unsigned short*)wqkv, NH * DH * HIDDEN / 4);
    cast_f32_bf16<<<(NKV * DH * HIDDEN / 4 + 255) / 256, 256, 0, stream>>>(Wk, (unsigned short*)(wqkv + (size_t)KOFF * HIDDEN), NKV * DH * HIDDEN / 4);
    cast_f32_bf16<<<(NKV * DH * HIDDEN / 4 + 255) / 256, 256, 0, stream>>>(Wv, (unsigned short*)(wqkv + (size_t)VOFF * HIDDEN), NKV * DH * HIDDEN / 4);
    cast_f32_bf16<<<(HIDDEN * NH * DH / 4 + 255) / 256, 256, 0, stream>>>(Wo, (unsigned short*)wob, HIDDEN * NH * DH / 4);

    // 2. fused QKV projection (256^2 8-phase, 192 blocks, full K)
    gemm256<bf16><<<dim3((S_LEN / 256) * (QKVW / 256), 1), 512, 0, stream>>>(
        hsb, wqkv, qkv, qkv, S_LEN, QKVW, HIDDEN, HIDDEN / 64);

    // 3. rmsnorm + rope in place on Q and K slices
    norm_rope<<<S_LEN * NH / 4, 256, 0, stream>>>(qkv, qw, cosp, sinp, 5, QKVW, 0);
    norm_rope<<<S_LEN * NKV / 4, 256, 0, stream>>>(qkv, kw, cosp, sinp, 3, QKVW, KOFF);

    // 4. V transpose
    transpose_v<<<dim3(NKV * DH / 32, S_LEN / 64), 256, 0, stream>>>(qkv, vtb, QKVW, VOFF);

    // 5. flash attention -> AO (reuse hsb); 8-wave KV-parallel blocks
    bf16* aob = hsb;
    flash_attn<<<512, 512, 0, stream>>>(qkv, vtb, aob);

    // 6. output projection, split-K x2 (256 blocks = full CU fill).
    //    Slice 0 -> out, slice 1 -> fp32 partial in the dead wqkv region (33.5MB <= 50MB).
    float* p1 = (float*)wqkv;
    gemm256<float><<<dim3((S_LEN / 256) * (HIDDEN / 256), 2), 512, 0, stream>>>(
        aob, wob, out, p1, S_LEN, HIDDEN, NH * DH, (NH * DH) / 2 / 64);

    // 7. split-K reduction: out += p1
    add_f32<<<(S_LEN * HIDDEN / 4 + 255) / 256, 256, 0, stream>>>(out, p1, S_LEN * HIDDEN / 4);
}

// Round 6
// 543.190 us; speedup vs baseline: 1.1188x; 1.1188x over previous
//
#include <hip/hip_runtime.h>
#include <hip/hip_bf16.h>

typedef __attribute__((ext_vector_type(8))) short bf16x8;
typedef __attribute__((ext_vector_type(4))) float f32x4;
typedef __hip_bfloat16 bf16;

#define S_LEN 2048
#define HIDDEN 4096
#define NH 32
#define NKV 8
#define DH 128
#define ROTD 64
#define QKVW 6144              // fused QKV row width (32*128 + 8*128 + 8*128)
#define KOFF 4096              // K column offset in fused buffer
#define VOFF 5120              // V column offset
#define ATT_SCALE 0.08838834764831845f
#define RMS_EPS 1e-6f
#define KPITCH 136             // Ks row pitch (elems): 272B = 17*16 -> aligned, 2-way banks
#define VPITCH 72              // Vs/Ps row pitch: 144B = 9*16 -> aligned, 2-way banks

#define BAR() __builtin_amdgcn_s_barrier()
#define VMCNT(n) asm volatile("s_waitcnt vmcnt(" #n ")" ::: "memory")
#define LGKM(n)  asm volatile("s_waitcnt lgkmcnt(" #n ")" ::: "memory")

static __device__ __forceinline__ unsigned short f2bu(float f) {
    bf16 h = __float2bfloat16(f);
    return __builtin_bit_cast(unsigned short, h);
}

static __device__ __forceinline__ void load_lds_16(const bf16* g, bf16* l) {
    __builtin_amdgcn_global_load_lds((const __attribute__((address_space(1))) void*)g,
                                     (__attribute__((address_space(3))) void*)l, 16, 0, 0);
}

// ---------------- fp32 -> bf16 cast (vectorized float4) ----------------
__global__ __launch_bounds__(256) void cast_f32_bf16(const float* __restrict__ src,
                                                     unsigned short* __restrict__ dst, int n4) {
    int i = blockIdx.x * 256 + threadIdx.x;
    if (i >= n4) return;
    float4 v = reinterpret_cast<const float4*>(src)[i];
    ushort4 o;
    o.x = f2bu(v.x); o.y = f2bu(v.y); o.z = f2bu(v.z); o.w = f2bu(v.w);
    reinterpret_cast<ushort4*>(dst)[i] = o;
}

// ---------------- fp32 in-place add (split-K reduction) ----------------
__global__ __launch_bounds__(256) void add_f32(float* __restrict__ dst,
                                               const float* __restrict__ src, int n4) {
    int i = blockIdx.x * 256 + threadIdx.x;
    if (i >= n4) return;
    float4 a = reinterpret_cast<float4*>(dst)[i];
    float4 b = reinterpret_cast<const float4*>(src)[i];
    a.x += b.x; a.y += b.y; a.z += b.z; a.w += b.w;
    reinterpret_cast<float4*>(dst)[i] = a;
}

// ---------------- C[M,N] = A[M,K] @ B[N,K]^T ----------------
// 256x256 tile, BK=64, 8 waves (2M x 4N), 8-phase schedule (T2+T3+T4+T5).
// Verified: 0 bank conflicts, no spill, 133 us @ QKV.
// NOTE (round-2 lesson): do NOT add extra register fragment sets; acc(128)+av/bv(64)
// is at the VGPR budget for 2 waves/EU — more sets spill to scratch.
#define LDA_SUB(bufi, half) do {                                                        \
    const bf16* _ab = &As[bufi][half][0];                                               \
    _Pragma("unroll") for (int mf = 0; mf < 4; ++mf) {                                  \
        const int _r = arow + mf * 16;                                                  \
        _Pragma("unroll") for (int kk = 0; kk < 2; ++kk)                                \
            av[mf][kk] = *reinterpret_cast<const bf16x8*>(                              \
                _ab + (((_r << 6) + kk * 32 + quad * 8) ^ xorv));                       \
    } } while (0)

#define LDB_SUB(bufi, half, set) do {                                                   \
    const bf16* _bb = &Bs[bufi][half][0];                                               \
    _Pragma("unroll") for (int nf = 0; nf < 2; ++nf) {                                  \
        const int _r = brow + nf * 16;                                                  \
        _Pragma("unroll") for (int kk = 0; kk < 2; ++kk)                                \
            bv[set][nf][kk] = *reinterpret_cast<const bf16x8*>(                         \
                _bb + (((_r << 6) + kk * 32 + quad * 8) ^ xorv));                       \
    } } while (0)

#define MMQ(mh, nh, set) do {                                                           \
    _Pragma("unroll") for (int mf = 0; mf < 4; ++mf)                                    \
    _Pragma("unroll") for (int nf = 0; nf < 2; ++nf)                                    \
    _Pragma("unroll") for (int kk = 0; kk < 2; ++kk)                                    \
        acc[mh][nh][mf][nf] = __builtin_amdgcn_mfma_f32_16x16x32_bf16(                  \
            av[mf][kk], bv[set][nf][kk], acc[mh][nh][mf][nf], 0, 0, 0);                 \
    } while (0)

#define STAGE_A(bufi, half, tau) do {                                                   \
    const bf16* _s = Abase + (size_t)(half) * 128 * K + (size_t)(tau) * 64;             \
    load_lds_16(_s + sro0, &As[bufi][half][e0]);                                        \
    load_lds_16(_s + sro1, &As[bufi][half][e1]); } while (0)

#define STAGE_B(bufi, half, tau) do {                                                   \
    const bf16* _s = Bbase + (size_t)(half) * 128 * K + (size_t)(tau) * 64;             \
    load_lds_16(_s + sro0, &Bs[bufi][half][e0]);                                        \
    load_lds_16(_s + sro1, &Bs[bufi][half][e1]); } while (0)

template <typename OutT>
__global__ __launch_bounds__(512, 2) void gemm256(const bf16* __restrict__ A,
                                                  const bf16* __restrict__ B,
                                                  OutT* __restrict__ C,
                                                  OutT* __restrict__ C2,
                                                  int M, int N, int K, int ktiles) {
    __shared__ bf16 As[2][2][128 * 64];
    __shared__ bf16 Bs[2][2][128 * 64];

    const int tid  = threadIdx.x;
    const int lane = tid & 63;
    const int lq   = lane & 15;
    const int quad = lane >> 4;
    const int wave = tid >> 6;
    const int wr   = wave >> 2;      // 0..1 (M)
    const int wc   = wave & 3;       // 0..3 (N)

    // XCD-aware block swizzle (grid.x here is a multiple of 8)
    const int nwg = gridDim.x;
    const int cpx = nwg >> 3;
    const int wg  = (blockIdx.x & 7) * cpx + (blockIdx.x >> 3);
    const int ntn = N >> 8;
    const int m0  = (wg / ntn) << 8;
    const int n0  = (wg % ntn) << 8;
    const int ksl = blockIdx.y;      // K-slice index (split-K)

    const int NT = ktiles;           // 64-wide K tiles this slice (even, >= 4)

    // ---- staging thread-constants: dest byte d -> pre-swizzled source offset o
    const int d0 = tid * 16;
    const int d1 = 8192 + tid * 16;
    const int o0 = d0 ^ (((d0 >> 7) & 7) << 4);
    const int o1 = d1 ^ (((d1 >> 7) & 7) << 4);
    const int e0 = d0 >> 1;          // LDS dest element offset (linear)
    const int e1 = d1 >> 1;
    const size_t sro0 = (size_t)((o0 >> 1) >> 6) * K + ((o0 >> 1) & 63);
    const size_t sro1 = (size_t)((o1 >> 1) >> 6) * K + ((o1 >> 1) & 63);
    const bf16* Abase = A + (size_t)m0 * K + (size_t)ksl * ktiles * 64;
    const bf16* Bbase = B + (size_t)n0 * K + (size_t)ksl * ktiles * 64;
    OutT* __restrict__ Cw = ksl ? C2 : C;

    // ---- fragment read constants
    const int arow = wr * 64 + lq;   // + mf*16  (row within A half)
    const int brow = wc * 32 + lq;   // + nf*16  (row within B half)
    const int xorv = (lq & 7) << 3;  // element-offset swizzle ((row&7)<<4 bytes)

    f32x4  acc[2][2][4][2] = {};
    bf16x8 av[4][2];                 // A-subtile for current mh
    bf16x8 bv[2][2][2];              // B-subtiles for nh=0 and nh=1 (both kept live)

    // ---- prologue: stage 7 half-tiles in sigma order, drain tile 0
    STAGE_B(0, 0, 0); STAGE_A(0, 0, 0); STAGE_B(0, 1, 0); STAGE_A(0, 1, 0);
    STAGE_B(1, 0, 1); STAGE_A(1, 0, 1); STAGE_B(1, 1, 1);
    VMCNT(6);
    BAR();

    for (int t = 0; t < NT; ++t) {
        const int buf = t & 1;

        // ---- p0: quadrant (0,0)
        LDA_SUB(buf, 0);
        LDB_SUB(buf, 0, 0);
        if (t + 1 < NT) STAGE_A(buf ^ 1, 1, t + 1);
        LGKM(8);
        BAR();
        LGKM(0);
        __builtin_amdgcn_s_setprio(1);
        MMQ(0, 0, 0);
        __builtin_amdgcn_s_setprio(0);
        BAR();

        // ---- p1: quadrant (0,1)
        LDB_SUB(buf, 1, 1);
        if (t + 2 < NT) STAGE_B(buf, 0, t + 2);
        BAR();
        LGKM(0);
        __builtin_amdgcn_s_setprio(1);
        MMQ(0, 1, 1);
        __builtin_amdgcn_s_setprio(0);
        BAR();

        // ---- p2: quadrant (1,1)
        LDA_SUB(buf, 1);
        if (t + 2 < NT) STAGE_A(buf, 0, t + 2);
        BAR();
        LGKM(0);
        __builtin_amdgcn_s_setprio(1);
        MMQ(1, 1, 1);
        __builtin_amdgcn_s_setprio(0);
        BAR();

        // ---- p3: quadrant (1,0)  (A from p2, B set 0 from p0 -- registers only)
        if (t + 2 < NT) STAGE_B(buf, 1, t + 2);
        BAR();
        __builtin_amdgcn_s_setprio(1);
        MMQ(1, 0, 0);
        __builtin_amdgcn_s_setprio(0);
        if (t < NT - 2) { VMCNT(6); } else { VMCNT(0); }   // boundary: next tile resident
        BAR();
    }

    // ---- epilogue: C-write (C/D layout: col = lane&15, row = quad*4 + r)
#pragma unroll
    for (int mh = 0; mh < 2; ++mh)
#pragma unroll
        for (int nh = 0; nh < 2; ++nh)
#pragma unroll
            for (int mf = 0; mf < 4; ++mf)
#pragma unroll
                for (int nf = 0; nf < 2; ++nf)
#pragma unroll
                    for (int r = 0; r < 4; ++r) {
                        const int row = m0 + mh * 128 + wr * 64 + mf * 16 + quad * 4 + r;
                        const int col = n0 + nh * 128 + wc * 32 + nf * 16 + lq;
                        const float v = acc[mh][nh][mf][nf][r];
                        const size_t idx = (size_t)row * N + col;
                        if constexpr (sizeof(OutT) == 2) Cw[idx] = __float2bfloat16(v);
                        else                             Cw[idx] = v;
                    }
}

// ---------------- fused RMSNorm + partial RoPE (in place, strided) ----------------
__global__ __launch_bounds__(256) void norm_rope(bf16* __restrict__ buf,
                                                 const float* __restrict__ w,
                                                 const float* __restrict__ cosp,
                                                 const float* __restrict__ sinp,
                                                 int log2nh, int stride, int coloff) {
    const int lane = threadIdx.x & 63;
    const int wave = threadIdx.x >> 6;
    const int row  = blockIdx.x * 4 + wave;
    const int s    = row >> log2nh;
    const int hh   = row & ((1 << log2nh) - 1);
    bf16* p = buf + (size_t)s * stride + coloff + hh * DH;

    float x1 = __bfloat162float(p[lane]);
    float x2 = __bfloat162float(p[64 + lane]);

    float ss = x1 * x1 + x2 * x2;
#pragma unroll
    for (int off = 1; off < 64; off <<= 1) ss += __shfl_xor(ss, off);
    float rs = rsqrtf(ss * (1.0f / 128.0f) + RMS_EPS);

    float y1 = x1 * rs * w[lane];
    float y2 = x2 * rs * w[64 + lane];

    float partner = __shfl_xor(y1, 32);
    float c  = cosp[(size_t)s * ROTD + lane];
    float sn = sinp[(size_t)s * ROTD + lane];
    float rot = (lane < 32) ? (y1 * c - partner * sn) : (y1 * c + partner * sn);

    p[lane]      = __float2bfloat16(rot);
    p[64 + lane] = __float2bfloat16(y2);
}

// ---------------- V transpose: qkv V cols -> vt(NKV*DH, S) ----------------
__global__ __launch_bounds__(256) void transpose_v(const bf16* __restrict__ v,
                                                   bf16* __restrict__ vt,
                                                   int stride, int colofs) {
    __shared__ bf16 t[32][65];
    const int c0 = blockIdx.x * 32;
    const int s0 = blockIdx.y * 64;
    {
        const int j  = threadIdx.x & 31;
        const int i0 = threadIdx.x >> 5;
#pragma unroll
        for (int p = 0; p < 8; ++p) {
            int si = p * 8 + i0;
            t[j][si] = v[(size_t)(s0 + si) * stride + colofs + c0 + j];
        }
    }
    __syncthreads();
    {
        const int ii = threadIdx.x & 63;
        const int j0 = threadIdx.x >> 6;
#pragma unroll
        for (int p = 0; p < 8; ++p) {
            int c = p * 4 + j0;
            vt[(size_t)(c0 + c) * S_LEN + s0 + ii] = t[c][ii];
        }
    }
}

// ---------------- block-cooperative MFMA flash attention (causal, GQA) ----------------
// Round-4 structure (reg-prefetch K/V pipeline, proven <=133us), launched as 1024
// single-q-block blocks (heavy first). LDS 45KB -> 3 blocks/CU -> 12 waves/CU.
// Round-5 lesson: do NOT serialize staging with vmcnt(0) per tile, and do NOT feed
// PV MFMAs from dependent global loads — the cross-iteration register prefetch into
// LDS is what hides HBM/L2 latency here.
struct FlashSmem {
    bf16 Ks[64][KPITCH];    // keys x dh
    bf16 Vs[128][VPITCH];   // dh x keys
    bf16 Ps[4][16][VPITCH]; // per-wave P round-trip
};

static __device__ __forceinline__ void attn_qblock(int q0, int n_iter, int h, int kvh,
                                                   const bf16* __restrict__ QKV,
                                                   const bf16* __restrict__ VT,
                                                   bf16* __restrict__ O,
                                                   FlashSmem* sm) {
    const int tid  = threadIdx.x;
    const int lane = tid & 63;
    const int wave = tid >> 6;
    const int lq   = lane & 15;
    const int quad = lane >> 4;
    const int qr0  = q0 + wave * 16;

    // Q fragments (A-layout), softmax scale folded
    bf16x8 qf[4];
    const bf16* qrow = QKV + (size_t)(qr0 + lq) * QKVW + h * DH + quad * 8;
#pragma unroll
    for (int i = 0; i < 4; ++i) {
        bf16x8 qv = *reinterpret_cast<const bf16x8*>(qrow + 32 * i);
#pragma unroll
        for (int j = 0; j < 8; ++j) {
            bf16 b = __builtin_bit_cast(bf16, (unsigned short)qv[j]);
            qv[j] = (short)__builtin_bit_cast(unsigned short,
                        __float2bfloat16(__bfloat162float(b) * ATT_SCALE));
        }
        qf[i] = qv;
    }

    f32x4 o[8];
#pragma unroll
    for (int t2 = 0; t2 < 8; ++t2) o[t2] = (f32x4){0.f, 0.f, 0.f, 0.f};
    float m_i[4], l_i[4];
#pragma unroll
    for (int r = 0; r < 4; ++r) { m_i[r] = -1e30f; l_i[r] = 0.f; }

    // staging addresses: K thread t -> key row t>>2, 64B chunk t&3
    //                    V thread t -> dh row  t>>1, 64B chunk t&1
    const bf16* kg = QKV + (size_t)(tid >> 2) * QKVW + KOFF + kvh * DH + (tid & 3) * 32;
    const bf16* vg = VT + (size_t)(kvh * DH + (tid >> 1)) * S_LEN + (tid & 1) * 32;
    bf16* ksl = &sm->Ks[tid >> 2][(tid & 3) * 32];
    bf16* vsl = &sm->Vs[tid >> 1][(tid & 1) * 32];
    bf16* pb  = &sm->Ps[wave][0][0];

    bf16x8 kreg[4], vreg[4];
#pragma unroll
    for (int c = 0; c < 4; ++c) {
        kreg[c] = *reinterpret_cast<const bf16x8*>(kg + 8 * c);
        vreg[c] = *reinterpret_cast<const bf16x8*>(vg + 8 * c);
    }

    for (int kt = 0; kt < n_iter; ++kt) {
        const int k0 = kt * 64;
#pragma unroll
        for (int c = 0; c < 4; ++c) {
            *reinterpret_cast<bf16x8*>(ksl + 8 * c) = kreg[c];
            *reinterpret_cast<bf16x8*>(vsl + 8 * c) = vreg[c];
        }
        __syncthreads();
        if (kt + 1 < n_iter) {
            const size_t kadv = (size_t)(kt + 1) * 64;
#pragma unroll
            for (int c = 0; c < 4; ++c) {
                kreg[c] = *reinterpret_cast<const bf16x8*>(kg + kadv * QKVW + 8 * c);
                vreg[c] = *reinterpret_cast<const bf16x8*>(vg + kadv + 8 * c);
            }
        }

        // QK^T on the staged tile
        float p[4][4];
#pragma unroll
        for (int t = 0; t < 4; ++t) {
            f32x4 sacc = (f32x4){0.f, 0.f, 0.f, 0.f};
#pragma unroll
            for (int i = 0; i < 4; ++i) {
                bf16x8 kf = *reinterpret_cast<const bf16x8*>(&sm->Ks[t * 16 + lq][quad * 8 + 32 * i]);
                sacc = __builtin_amdgcn_mfma_f32_16x16x32_bf16(qf[i], kf, sacc, 0, 0, 0);
            }
#pragma unroll
            for (int r = 0; r < 4; ++r) {
                int qi = qr0 + quad * 4 + r;
                int ki = k0 + t * 16 + lq;
                p[t][r] = (ki > qi) ? -1e30f : sacc[r];
            }
        }

        float rowmax[4];
#pragma unroll
        for (int r = 0; r < 4; ++r)
            rowmax[r] = fmaxf(fmaxf(p[0][r], p[1][r]), fmaxf(p[2][r], p[3][r]));
#pragma unroll
        for (int off = 1; off < 16; off <<= 1)
#pragma unroll
            for (int r = 0; r < 4; ++r) rowmax[r] = fmaxf(rowmax[r], __shfl_xor(rowmax[r], off));

        float alpha[4];
#pragma unroll
        for (int r = 0; r < 4; ++r) {
            float mn = fmaxf(m_i[r], rowmax[r]);
            alpha[r] = __expf(m_i[r] - mn);
            m_i[r] = mn;
        }
#pragma unroll
        for (int t = 0; t < 4; ++t)
#pragma unroll
            for (int r = 0; r < 4; ++r) p[t][r] = __expf(p[t][r] - m_i[r]);

        float rsum[4];
#pragma unroll
        for (int r = 0; r < 4; ++r) rsum[r] = (p[0][r] + p[1][r]) + (p[2][r] + p[3][r]);
#pragma unroll
        for (int off = 1; off < 16; off <<= 1)
#pragma unroll
            for (int r = 0; r < 4; ++r) rsum[r] += __shfl_xor(rsum[r], off);
#pragma unroll
        for (int r = 0; r < 4; ++r) l_i[r] = l_i[r] * alpha[r] + rsum[r];

        // P (C-layout) -> per-wave LDS -> A-layout
#pragma unroll
        for (int t = 0; t < 4; ++t)
#pragma unroll
            for (int r = 0; r < 4; ++r)
                pb[(quad * 4 + r) * VPITCH + t * 16 + lq] = __float2bfloat16(p[t][r]);
        __threadfence_block();

#pragma unroll
        for (int t2 = 0; t2 < 8; ++t2)
#pragma unroll
            for (int r = 0; r < 4; ++r) o[t2][r] *= alpha[r];

#pragma unroll
        for (int hh = 0; hh < 2; ++hh) {
            bf16x8 pa = *reinterpret_cast<const bf16x8*>(pb + lq * VPITCH + hh * 32 + quad * 8);
#pragma unroll
            for (int t2 = 0; t2 < 8; ++t2) {
                bf16x8 vf = *reinterpret_cast<const bf16x8*>(&sm->Vs[t2 * 16 + lq][hh * 32 + quad * 8]);
                o[t2] = __builtin_amdgcn_mfma_f32_16x16x32_bf16(pa, vf, o[t2], 0, 0, 0);
            }
        }
        __syncthreads();   // protect Ks/Vs (and Ps) before next staging store
    }

#pragma unroll
    for (int r = 0; r < 4; ++r) l_i[r] = 1.0f / l_i[r];
#pragma unroll
    for (int t2 = 0; t2 < 8; ++t2)
#pragma unroll
        for (int r = 0; r < 4; ++r)
            O[(size_t)(qr0 + quad * 4 + r) * (NH * DH) + h * DH + t2 * 16 + lq] =
                __float2bfloat16(o[t2][r] * l_i[r]);
}

__global__ __launch_bounds__(256) void flash_attn(const bf16* __restrict__ QKV,
                                                  const bf16* __restrict__ VT,
                                                  bf16* __restrict__ O) {
    __shared__ FlashSmem sm;
    const int b  = blockIdx.x;       // 0..1023: one 64-row q-block each
    const int h  = b & 31;
    const int qb = 31 - (b >> 5);    // heavy q-blocks (most k-tiles) launch first
    const int kvh = h >> 2;
    attn_qblock(qb * 64, qb + 1, h, kvh, QKV, VT, O, &sm);
}

extern "C" void kernel_launch(void* const* d_in, const int* in_sizes, int n_in,
                              void* d_out, int out_size, void* d_ws, size_t ws_size,
                              hipStream_t stream) {
    const float* hs   = (const float*)d_in[0];
    const float* cosp = (const float*)d_in[1];
    const float* sinp = (const float*)d_in[2];
    const float* Wq   = (const float*)d_in[3];
    const float* Wk   = (const float*)d_in[4];
    const float* Wv   = (const float*)d_in[5];
    const float* Wo   = (const float*)d_in[6];
    const float* qw   = (const float*)d_in[7];
    const float* kw   = (const float*)d_in[8];
    float* out = (float*)d_out;

    char* ws = (char*)d_ws;
    size_t off = 0;
    auto carve = [&](size_t bytes) { char* p = ws + off; off += (bytes + 255) & ~(size_t)255; return p; };

    bf16* hsb  = (bf16*)carve((size_t)S_LEN * HIDDEN * 2);          // hidden bf16; reused as AO
    bf16* wqkv = (bf16*)carve((size_t)QKVW * HIDDEN * 2);           // fused [6144, 4096]; reused as split-K partial
    bf16* wob  = (bf16*)carve((size_t)HIDDEN * NH * DH * 2);
    bf16* qkv  = (bf16*)carve((size_t)S_LEN * QKVW * 2);            // [S, 6144]
    bf16* vtb  = (bf16*)carve((size_t)NKV * DH * S_LEN * 2);

    // 1. casts
    cast_f32_bf16<<<(S_LEN * HIDDEN / 4 + 255) / 256, 256, 0, stream>>>(hs, (unsigned short*)hsb, S_LEN * HIDDEN / 4);
    cast_f32_bf16<<<(NH * DH * HIDDEN / 4 + 255) / 256, 256, 0, stream>>>(Wq, (unsigned short*)wqkv, NH * DH * HIDDEN / 4);
    cast_f32_bf16<<<(NKV * DH * HIDDEN / 4 + 255) / 256, 256, 0, stream>>>(Wk, (unsigned short*)(wqkv + (size_t)KOFF * HIDDEN), NKV * DH * HIDDEN / 4);
    cast_f32_bf16<<<(NKV * DH * HIDDEN / 4 + 255) / 256, 256, 0, stream>>>(Wv, (unsigned short*)(wqkv + (size_t)VOFF * HIDDEN), NKV * DH * HIDDEN / 4);
    cast_f32_bf16<<<(HIDDEN * NH * DH / 4 + 255) / 256, 256, 0, stream>>>(Wo, (unsigned short*)wob, HIDDEN * NH * DH / 4);

    // 2. fused QKV projection (256^2 8-phase, 192 blocks, full K)
    gemm256<bf16><<<dim3((S_LEN / 256) * (QKVW / 256), 1), 512, 0, stream>>>(
        hsb, wqkv, qkv, qkv, S_LEN, QKVW, HIDDEN, HIDDEN / 64);

    // 3. rmsnorm + rope in place on Q and K slices
    norm_rope<<<S_LEN * NH / 4, 256, 0, stream>>>(qkv, qw, cosp, sinp, 5, QKVW, 0);
    norm_rope<<<S_LEN * NKV / 4, 256, 0, stream>>>(qkv, kw, cosp, sinp, 3, QKVW, KOFF);

    // 4. V transpose
    transpose_v<<<dim3(NKV * DH / 32, S_LEN / 64), 256, 0, stream>>>(qkv, vtb, QKVW, VOFF);

    // 5. flash attention -> AO (reuse hsb); 1024 single-q-block blocks, heavy first
    bf16* aob = hsb;
    flash_attn<<<1024, 256, 0, stream>>>(qkv, vtb, aob);

    // 6. output projection, split-K x2 (256 blocks = full CU fill).
    //    Slice 0 -> out, slice 1 -> fp32 partial in the dead wqkv region (33.5MB <= 50MB).
    float* p1 = (float*)wqkv;
    gemm256<float><<<dim3((S_LEN / 256) * (HIDDEN / 256), 2), 512, 0, stream>>>(
        aob, wob, out, p1, S_LEN, HIDDEN, NH * DH, (NH * DH) / 2 / 64);

    // 7. split-K reduction: out += p1
    add_f32<<<(S_LEN * HIDDEN / 4 + 255) / 256, 256, 0, stream>>>(out, p1, S_LEN * HIDDEN / 4);
}

// Round 7
// 539.914 us; speedup vs baseline: 1.1256x; 1.0061x over previous
//
#include <hip/hip_runtime.h>
#include <hip/hip_bf16.h>

typedef __attribute__((ext_vector_type(8))) short bf16x8;
typedef __attribute__((ext_vector_type(4))) float f32x4;
typedef __hip_bfloat16 bf16;

#define S_LEN 2048
#define HIDDEN 4096
#define NH 32
#define NKV 8
#define DH 128
#define ROTD 64
#define QKVW 6144              // fused QKV row width (32*128 + 8*128 + 8*128)
#define KOFF 4096              // K column offset in fused buffer
#define VOFF 5120              // V column offset
#define ATT_SCALE 0.08838834764831845f
#define RMS_EPS 1e-6f
#define KPITCH 136             // Ks row pitch (elems): 272B = 17*16 -> aligned, 2-way banks
#define VPITCH 72              // Vs/Ps row pitch: 144B = 9*16 -> aligned, 2-way banks

#define BAR() __builtin_amdgcn_s_barrier()
#define VMCNT(n) asm volatile("s_waitcnt vmcnt(" #n ")" ::: "memory")
#define LGKM(n)  asm volatile("s_waitcnt lgkmcnt(" #n ")" ::: "memory")

static __device__ __forceinline__ unsigned short f2bu(float f) {
    bf16 h = __float2bfloat16(f);
    return __builtin_bit_cast(unsigned short, h);
}

static __device__ __forceinline__ void load_lds_16(const bf16* g, bf16* l) {
    __builtin_amdgcn_global_load_lds((const __attribute__((address_space(1))) void*)g,
                                     (__attribute__((address_space(3))) void*)l, 16, 0, 0);
}

// ---------------- fused fp32 -> bf16 cast for all 5 inputs (one launch) ----------------
// segments (float4 units): hs 2097152 | Wq 4194304 | Wk 1048576 | Wv 1048576 | Wo 4194304
__global__ __launch_bounds__(256) void cast_all(const float* __restrict__ hs,
                                                const float* __restrict__ Wq,
                                                const float* __restrict__ Wk,
                                                const float* __restrict__ Wv,
                                                const float* __restrict__ Wo,
                                                unsigned short* __restrict__ hsb,
                                                unsigned short* __restrict__ wqkv,
                                                unsigned short* __restrict__ wob) {
    const int i = blockIdx.x * 256 + threadIdx.x;
    const float* src; unsigned short* dst; int j;
    if (i < 2097152)      { src = hs; dst = hsb;  j = i; }
    else if (i < 6291456) { src = Wq; dst = wqkv; j = i - 2097152; }
    else if (i < 7340032) { src = Wk; dst = wqkv + (size_t)KOFF * HIDDEN; j = i - 6291456; }
    else if (i < 8388608) { src = Wv; dst = wqkv + (size_t)VOFF * HIDDEN; j = i - 7340032; }
    else                  { src = Wo; dst = wob;  j = i - 8388608; }
    float4 v = reinterpret_cast<const float4*>(src)[j];
    ushort4 o;
    o.x = f2bu(v.x); o.y = f2bu(v.y); o.z = f2bu(v.z); o.w = f2bu(v.w);
    reinterpret_cast<ushort4*>(dst)[j] = o;
}

// ---------------- C[M,N] = A[M,K] @ B[N,K]^T, 256^2 8-phase (QKV projection) ----------------
// Verified: 0 bank conflicts, no spill, ~133 us @ QKV.
// NOTE (round-2 lesson): do NOT add extra register fragment sets; acc(128)+av/bv(64)
// is at the VGPR budget for 2 waves/EU — more sets spill to scratch.
// swz2d=1 (requires grid.x==192, 8 m-tiles x 24 n-tiles): each XCD owns a 4m x 6n patch
// so B half-tiles are shared by 4 blocks and A by 6 within an XCD's L2 per K-step
// (old row-swizzle: zero B reuse -> 400 MB aggregate B re-fetch from L3).
#define LDA_SUB(bufi, half) do {                                                        \
    const bf16* _ab = &As[bufi][half][0];                                               \
    _Pragma("unroll") for (int mf = 0; mf < 4; ++mf) {                                  \
        const int _r = arow + mf * 16;                                                  \
        _Pragma("unroll") for (int kk = 0; kk < 2; ++kk)                                \
            av[mf][kk] = *reinterpret_cast<const bf16x8*>(                              \
                _ab + (((_r << 6) + kk * 32 + quad * 8) ^ xorv));                       \
    } } while (0)

#define LDB_SUB(bufi, half, set) do {                                                   \
    const bf16* _bb = &Bs[bufi][half][0];                                               \
    _Pragma("unroll") for (int nf = 0; nf < 2; ++nf) {                                  \
        const int _r = brow + nf * 16;                                                  \
        _Pragma("unroll") for (int kk = 0; kk < 2; ++kk)                                \
            bv[set][nf][kk] = *reinterpret_cast<const bf16x8*>(                         \
                _bb + (((_r << 6) + kk * 32 + quad * 8) ^ xorv));                       \
    } } while (0)

#define MMQ(mh, nh, set) do {                                                           \
    _Pragma("unroll") for (int mf = 0; mf < 4; ++mf)                                    \
    _Pragma("unroll") for (int nf = 0; nf < 2; ++nf)                                    \
    _Pragma("unroll") for (int kk = 0; kk < 2; ++kk)                                    \
        acc[mh][nh][mf][nf] = __builtin_amdgcn_mfma_f32_16x16x32_bf16(                  \
            av[mf][kk], bv[set][nf][kk], acc[mh][nh][mf][nf], 0, 0, 0);                 \
    } while (0)

#define STAGE_A(bufi, half, tau) do {                                                   \
    const bf16* _s = Abase + (size_t)(half) * 128 * K + (size_t)(tau) * 64;             \
    load_lds_16(_s + sro0, &As[bufi][half][e0]);                                        \
    load_lds_16(_s + sro1, &As[bufi][half][e1]); } while (0)

#define STAGE_B(bufi, half, tau) do {                                                   \
    const bf16* _s = Bbase + (size_t)(half) * 128 * K + (size_t)(tau) * 64;             \
    load_lds_16(_s + sro0, &Bs[bufi][half][e0]);                                        \
    load_lds_16(_s + sro1, &Bs[bufi][half][e1]); } while (0)

template <typename OutT>
__global__ __launch_bounds__(512, 2) void gemm256(const bf16* __restrict__ A,
                                                  const bf16* __restrict__ B,
                                                  OutT* __restrict__ C,
                                                  int M, int N, int K, int ktiles,
                                                  int swz2d) {
    __shared__ bf16 As[2][2][128 * 64];
    __shared__ bf16 Bs[2][2][128 * 64];

    const int tid  = threadIdx.x;
    const int lane = tid & 63;
    const int lq   = lane & 15;
    const int quad = lane >> 4;
    const int wave = tid >> 6;
    const int wr   = wave >> 2;      // 0..1 (M)
    const int wc   = wave & 3;       // 0..3 (N)

    int m0, n0;
    if (swz2d) {
        // 8 XCDs as 2x4 patches of 4m x 6n tiles (bijective for grid.x == 192)
        const int xcd = blockIdx.x & 7;
        const int loc = blockIdx.x >> 3;
        const int lm  = loc / 6;
        const int ln  = loc - lm * 6;
        m0 = (((xcd >> 2) << 2) + lm) << 8;
        n0 = ((xcd & 3) * 6 + ln) << 8;
    } else {
        const int nwg = gridDim.x;
        const int cpx = nwg >> 3;
        const int wg  = (blockIdx.x & 7) * cpx + (blockIdx.x >> 3);
        const int ntn = N >> 8;
        m0 = (wg / ntn) << 8;
        n0 = (wg % ntn) << 8;
    }

    const int NT = ktiles;           // 64-wide K tiles (even, >= 4)

    // ---- staging thread-constants: dest byte d -> pre-swizzled source offset o
    const int d0 = tid * 16;
    const int d1 = 8192 + tid * 16;
    const int o0 = d0 ^ (((d0 >> 7) & 7) << 4);
    const int o1 = d1 ^ (((d1 >> 7) & 7) << 4);
    const int e0 = d0 >> 1;          // LDS dest element offset (linear)
    const int e1 = d1 >> 1;
    const size_t sro0 = (size_t)((o0 >> 1) >> 6) * K + ((o0 >> 1) & 63);
    const size_t sro1 = (size_t)((o1 >> 1) >> 6) * K + ((o1 >> 1) & 63);
    const bf16* Abase = A + (size_t)m0 * K;
    const bf16* Bbase = B + (size_t)n0 * K;

    // ---- fragment read constants
    const int arow = wr * 64 + lq;   // + mf*16  (row within A half)
    const int brow = wc * 32 + lq;   // + nf*16  (row within B half)
    const int xorv = (lq & 7) << 3;  // element-offset swizzle ((row&7)<<4 bytes)

    f32x4  acc[2][2][4][2] = {};
    bf16x8 av[4][2];                 // A-subtile for current mh
    bf16x8 bv[2][2][2];              // B-subtiles for nh=0 and nh=1 (both kept live)

    // ---- prologue: stage 7 half-tiles in sigma order, drain tile 0
    STAGE_B(0, 0, 0); STAGE_A(0, 0, 0); STAGE_B(0, 1, 0); STAGE_A(0, 1, 0);
    STAGE_B(1, 0, 1); STAGE_A(1, 0, 1); STAGE_B(1, 1, 1);
    VMCNT(6);
    BAR();

    for (int t = 0; t < NT; ++t) {
        const int buf = t & 1;

        // ---- p0: quadrant (0,0)
        LDA_SUB(buf, 0);
        LDB_SUB(buf, 0, 0);
        if (t + 1 < NT) STAGE_A(buf ^ 1, 1, t + 1);
        LGKM(8);
        BAR();
        LGKM(0);
        __builtin_amdgcn_s_setprio(1);
        MMQ(0, 0, 0);
        __builtin_amdgcn_s_setprio(0);
        BAR();

        // ---- p1: quadrant (0,1)
        LDB_SUB(buf, 1, 1);
        if (t + 2 < NT) STAGE_B(buf, 0, t + 2);
        BAR();
        LGKM(0);
        __builtin_amdgcn_s_setprio(1);
        MMQ(0, 1, 1);
        __builtin_amdgcn_s_setprio(0);
        BAR();

        // ---- p2: quadrant (1,1)
        LDA_SUB(buf, 1);
        if (t + 2 < NT) STAGE_A(buf, 0, t + 2);
        BAR();
        LGKM(0);
        __builtin_amdgcn_s_setprio(1);
        MMQ(1, 1, 1);
        __builtin_amdgcn_s_setprio(0);
        BAR();

        // ---- p3: quadrant (1,0)  (A from p2, B set 0 from p0 -- registers only)
        if (t + 2 < NT) STAGE_B(buf, 1, t + 2);
        BAR();
        __builtin_amdgcn_s_setprio(1);
        MMQ(1, 0, 0);
        __builtin_amdgcn_s_setprio(0);
        if (t < NT - 2) { VMCNT(6); } else { VMCNT(0); }   // boundary: next tile resident
        BAR();
    }

    // ---- epilogue: C-write (C/D layout: col = lane&15, row = quad*4 + r)
#pragma unroll
    for (int mh = 0; mh < 2; ++mh)
#pragma unroll
        for (int nh = 0; nh < 2; ++nh)
#pragma unroll
            for (int mf = 0; mf < 4; ++mf)
#pragma unroll
                for (int nf = 0; nf < 2; ++nf)
#pragma unroll
                    for (int r = 0; r < 4; ++r) {
                        const int row = m0 + mh * 128 + wr * 64 + mf * 16 + quad * 4 + r;
                        const int col = n0 + nh * 128 + wc * 32 + nf * 16 + lq;
                        const float v = acc[mh][nh][mf][nf][r];
                        const size_t idx = (size_t)row * N + col;
                        if constexpr (sizeof(OutT) == 2) C[idx] = __float2bfloat16(v);
                        else                             C[idx] = v;
                    }
}

// ---------------- C[M,N] = A[M,K] @ B[N,K]^T, m97-style 128^2 (output projection) ----------------
// Round-0 verified kernel. At K=1024 / grid 512 (2 blocks/CU) this beats 256^2 split-K
// + reduction pass: no partial buffer, no add kernel, full CU fill.
template <typename OutT>
__global__ __launch_bounds__(256) void gemm_lds(const bf16* __restrict__ A,
                                                const bf16* __restrict__ B,
                                                OutT* __restrict__ C,
                                                int M, int N, int K) {
    __shared__ bf16 As[128 * 32];
    __shared__ bf16 Bs[128 * 32];
    const int tid  = threadIdx.x;
    const int lane = tid & 63;
    const int wave = tid >> 6;
    const int lq   = lane & 15;
    const int quad = lane >> 4;
    const int m0 = blockIdx.y * 128;
    const int n0 = blockIdx.x * 128;
    const int wm = (wave & 1) * 64;
    const int wn = (wave >> 1) * 64;

    f32x4 acc[4][4] = {};

    const int ar = tid >> 2;
    const int ac = (tid & 3) * 8;
    const bf16* Ag0 = A + (size_t)(m0 + ar) * K + ac;
    const bf16* Ag1 = Ag0 + (size_t)64 * K;
    const bf16* Bg0 = B + (size_t)(n0 + ar) * K + ac;
    const bf16* Bg1 = Bg0 + (size_t)64 * K;
    bf16* Asl0 = As + wave * 512;
    bf16* Asl1 = As + wave * 512 + 2048;
    bf16* Bsl0 = Bs + wave * 512;
    bf16* Bsl1 = Bs + wave * 512 + 2048;

    for (int k0 = 0; k0 < K; k0 += 32) {
        load_lds_16(Ag0 + k0, Asl0);
        load_lds_16(Ag1 + k0, Asl1);
        load_lds_16(Bg0 + k0, Bsl0);
        load_lds_16(Bg1 + k0, Bsl1);
        __syncthreads();
        bf16x8 avv[4], bvv[4];
#pragma unroll
        for (int i = 0; i < 4; ++i)
            avv[i] = *reinterpret_cast<const bf16x8*>(As + (wm + i * 16 + lq) * 32 + quad * 8);
#pragma unroll
        for (int i = 0; i < 4; ++i)
            bvv[i] = *reinterpret_cast<const bf16x8*>(Bs + (wn + i * 16 + lq) * 32 + quad * 8);
#pragma unroll
        for (int mt = 0; mt < 4; ++mt)
#pragma unroll
            for (int nt = 0; nt < 4; ++nt)
                acc[mt][nt] = __builtin_amdgcn_mfma_f32_16x16x32_bf16(avv[mt], bvv[nt], acc[mt][nt], 0, 0, 0);
        __syncthreads();
    }

#pragma unroll
    for (int mt = 0; mt < 4; ++mt)
#pragma unroll
        for (int nt = 0; nt < 4; ++nt)
#pragma unroll
            for (int r = 0; r < 4; ++r) {
                float v = acc[mt][nt][r];
                size_t idx = (size_t)(m0 + wm + mt * 16 + quad * 4 + r) * N + n0 + wn + nt * 16 + lq;
                if constexpr (sizeof(OutT) == 2) C[idx] = __float2bfloat16(v);
                else                             C[idx] = v;
            }
}

// ---------------- fused RMSNorm + partial RoPE (in place, strided) ----------------
__global__ __launch_bounds__(256) void norm_rope(bf16* __restrict__ buf,
                                                 const float* __restrict__ w,
                                                 const float* __restrict__ cosp,
                                                 const float* __restrict__ sinp,
                                                 int log2nh, int stride, int coloff) {
    const int lane = threadIdx.x & 63;
    const int wave = threadIdx.x >> 6;
    const int row  = blockIdx.x * 4 + wave;
    const int s    = row >> log2nh;
    const int hh   = row & ((1 << log2nh) - 1);
    bf16* p = buf + (size_t)s * stride + coloff + hh * DH;

    float x1 = __bfloat162float(p[lane]);
    float x2 = __bfloat162float(p[64 + lane]);

    float ss = x1 * x1 + x2 * x2;
#pragma unroll
    for (int off = 1; off < 64; off <<= 1) ss += __shfl_xor(ss, off);
    float rs = rsqrtf(ss * (1.0f / 128.0f) + RMS_EPS);

    float y1 = x1 * rs * w[lane];
    float y2 = x2 * rs * w[64 + lane];

    float partner = __shfl_xor(y1, 32);
    float c  = cosp[(size_t)s * ROTD + lane];
    float sn = sinp[(size_t)s * ROTD + lane];
    float rot = (lane < 32) ? (y1 * c - partner * sn) : (y1 * c + partner * sn);

    p[lane]      = __float2bfloat16(rot);
    p[64 + lane] = __float2bfloat16(y2);
}

// ---------------- V transpose: qkv V cols -> vt(NKV*DH, S) ----------------
__global__ __launch_bounds__(256) void transpose_v(const bf16* __restrict__ v,
                                                   bf16* __restrict__ vt,
                                                   int stride, int colofs) {
    __shared__ bf16 t[32][65];
    const int c0 = blockIdx.x * 32;
    const int s0 = blockIdx.y * 64;
    {
        const int j  = threadIdx.x & 31;
        const int i0 = threadIdx.x >> 5;
#pragma unroll
        for (int p = 0; p < 8; ++p) {
            int si = p * 8 + i0;
            t[j][si] = v[(size_t)(s0 + si) * stride + colofs + c0 + j];
        }
    }
    __syncthreads();
    {
        const int ii = threadIdx.x & 63;
        const int j0 = threadIdx.x >> 6;
#pragma unroll
        for (int p = 0; p < 8; ++p) {
            int c = p * 4 + j0;
            vt[(size_t)(c0 + c) * S_LEN + s0 + ii] = t[c][ii];
        }
    }
}

// ---------------- block-cooperative MFMA flash attention (causal, GQA) ----------------
// Round-4 inner structure (reg-prefetch K/V pipeline); 1024 single-q-block blocks,
// heavy first. Round-5 lesson: never serialize staging with per-tile vmcnt(0) and
// never feed PV MFMAs from dependent global loads. Round-6 lesson: attn is
// serial-chain latency-bound — extra TLP (2->3 blocks/CU) is neutral.
struct FlashSmem {
    bf16 Ks[64][KPITCH];    // keys x dh
    bf16 Vs[128][VPITCH];   // dh x keys
    bf16 Ps[4][16][VPITCH]; // per-wave P round-trip
};

static __device__ __forceinline__ void attn_qblock(int q0, int n_iter, int h, int kvh,
                                                   const bf16* __restrict__ QKV,
                                                   const bf16* __restrict__ VT,
                                                   bf16* __restrict__ O,
                                                   FlashSmem* sm) {
    const int tid  = threadIdx.x;
    const int lane = tid & 63;
    const int wave = tid >> 6;
    const int lq   = lane & 15;
    const int quad = lane >> 4;
    const int qr0  = q0 + wave * 16;

    // Q fragments (A-layout), softmax scale folded
    bf16x8 qf[4];
    const bf16* qrow = QKV + (size_t)(qr0 + lq) * QKVW + h * DH + quad * 8;
#pragma unroll
    for (int i = 0; i < 4; ++i) {
        bf16x8 qv = *reinterpret_cast<const bf16x8*>(qrow + 32 * i);
#pragma unroll
        for (int j = 0; j < 8; ++j) {
            bf16 b = __builtin_bit_cast(bf16, (unsigned short)qv[j]);
            qv[j] = (short)__builtin_bit_cast(unsigned short,
                        __float2bfloat16(__bfloat162float(b) * ATT_SCALE));
        }
        qf[i] = qv;
    }

    f32x4 o[8];
#pragma unroll
    for (int t2 = 0; t2 < 8; ++t2) o[t2] = (f32x4){0.f, 0.f, 0.f, 0.f};
    float m_i[4], l_i[4];
#pragma unroll
    for (int r = 0; r < 4; ++r) { m_i[r] = -1e30f; l_i[r] = 0.f; }

    // staging addresses: K thread t -> key row t>>2, 64B chunk t&3
    //                    V thread t -> dh row  t>>1, 64B chunk t&1
    const bf16* kg = QKV + (size_t)(tid >> 2) * QKVW + KOFF + kvh * DH + (tid & 3) * 32;
    const bf16* vg = VT + (size_t)(kvh * DH + (tid >> 1)) * S_LEN + (tid & 1) * 32;
    bf16* ksl = &sm->Ks[tid >> 2][(tid & 3) * 32];
    bf16* vsl = &sm->Vs[tid >> 1][(tid & 1) * 32];
    bf16* pb  = &sm->Ps[wave][0][0];

    bf16x8 kreg[4], vreg[4];
#pragma unroll
    for (int c = 0; c < 4; ++c) {
        kreg[c] = *reinterpret_cast<const bf16x8*>(kg + 8 * c);
        vreg[c] = *reinterpret_cast<const bf16x8*>(vg + 8 * c);
    }

    for (int kt = 0; kt < n_iter; ++kt) {
        const int k0 = kt * 64;
#pragma unroll
        for (int c = 0; c < 4; ++c) {
            *reinterpret_cast<bf16x8*>(ksl + 8 * c) = kreg[c];
            *reinterpret_cast<bf16x8*>(vsl + 8 * c) = vreg[c];
        }
        __syncthreads();
        if (kt + 1 < n_iter) {
            const size_t kadv = (size_t)(kt + 1) * 64;
#pragma unroll
            for (int c = 0; c < 4; ++c) {
                kreg[c] = *reinterpret_cast<const bf16x8*>(kg + kadv * QKVW + 8 * c);
                vreg[c] = *reinterpret_cast<const bf16x8*>(vg + kadv + 8 * c);
            }
        }

        // QK^T on the staged tile
        float p[4][4];
#pragma unroll
        for (int t = 0; t < 4; ++t) {
            f32x4 sacc = (f32x4){0.f, 0.f, 0.f, 0.f};
#pragma unroll
            for (int i = 0; i < 4; ++i) {
                bf16x8 kf = *reinterpret_cast<const bf16x8*>(&sm->Ks[t * 16 + lq][quad * 8 + 32 * i]);
                sacc = __builtin_amdgcn_mfma_f32_16x16x32_bf16(qf[i], kf, sacc, 0, 0, 0);
            }
#pragma unroll
            for (int r = 0; r < 4; ++r) {
                int qi = qr0 + quad * 4 + r;
                int ki = k0 + t * 16 + lq;
                p[t][r] = (ki > qi) ? -1e30f : sacc[r];
            }
        }

        float rowmax[4];
#pragma unroll
        for (int r = 0; r < 4; ++r)
            rowmax[r] = fmaxf(fmaxf(p[0][r], p[1][r]), fmaxf(p[2][r], p[3][r]));
#pragma unroll
        for (int off = 1; off < 16; off <<= 1)
#pragma unroll
            for (int r = 0; r < 4; ++r) rowmax[r] = fmaxf(rowmax[r], __shfl_xor(rowmax[r], off));

        float alpha[4];
#pragma unroll
        for (int r = 0; r < 4; ++r) {
            float mn = fmaxf(m_i[r], rowmax[r]);
            alpha[r] = __expf(m_i[r] - mn);
            m_i[r] = mn;
        }
#pragma unroll
        for (int t = 0; t < 4; ++t)
#pragma unroll
            for (int r = 0; r < 4; ++r) p[t][r] = __expf(p[t][r] - m_i[r]);

        float rsum[4];
#pragma unroll
        for (int r = 0; r < 4; ++r) rsum[r] = (p[0][r] + p[1][r]) + (p[2][r] + p[3][r]);
#pragma unroll
        for (int off = 1; off < 16; off <<= 1)
#pragma unroll
            for (int r = 0; r < 4; ++r) rsum[r] += __shfl_xor(rsum[r], off);
#pragma unroll
        for (int r = 0; r < 4; ++r) l_i[r] = l_i[r] * alpha[r] + rsum[r];

        // P (C-layout) -> per-wave LDS -> A-layout
#pragma unroll
        for (int t = 0; t < 4; ++t)
#pragma unroll
            for (int r = 0; r < 4; ++r)
                pb[(quad * 4 + r) * VPITCH + t * 16 + lq] = __float2bfloat16(p[t][r]);
        __threadfence_block();

#pragma unroll
        for (int t2 = 0; t2 < 8; ++t2)
#pragma unroll
            for (int r = 0; r < 4; ++r) o[t2][r] *= alpha[r];

#pragma unroll
        for (int hh = 0; hh < 2; ++hh) {
            bf16x8 pa = *reinterpret_cast<const bf16x8*>(pb + lq * VPITCH + hh * 32 + quad * 8);
#pragma unroll
            for (int t2 = 0; t2 < 8; ++t2) {
                bf16x8 vf = *reinterpret_cast<const bf16x8*>(&sm->Vs[t2 * 16 + lq][hh * 32 + quad * 8]);
                o[t2] = __builtin_amdgcn_mfma_f32_16x16x32_bf16(pa, vf, o[t2], 0, 0, 0);
            }
        }
        __syncthreads();   // protect Ks/Vs (and Ps) before next staging store
    }

#pragma unroll
    for (int r = 0; r < 4; ++r) l_i[r] = 1.0f / l_i[r];
#pragma unroll
    for (int t2 = 0; t2 < 8; ++t2)
#pragma unroll
        for (int r = 0; r < 4; ++r)
            O[(size_t)(qr0 + quad * 4 + r) * (NH * DH) + h * DH + t2 * 16 + lq] =
                __float2bfloat16(o[t2][r] * l_i[r]);
}

__global__ __launch_bounds__(256) void flash_attn(const bf16* __restrict__ QKV,
                                                  const bf16* __restrict__ VT,
                                                  bf16* __restrict__ O) {
    __shared__ FlashSmem sm;
    const int b  = blockIdx.x;       // 0..1023: one 64-row q-block each
    const int h  = b & 31;
    const int qb = 31 - (b >> 5);    // heavy q-blocks (most k-tiles) launch first
    const int kvh = h >> 2;
    attn_qblock(qb * 64, qb + 1, h, kvh, QKV, VT, O, &sm);
}

extern "C" void kernel_launch(void* const* d_in, const int* in_sizes, int n_in,
                              void* d_out, int out_size, void* d_ws, size_t ws_size,
                              hipStream_t stream) {
    const float* hs   = (const float*)d_in[0];
    const float* cosp = (const float*)d_in[1];
    const float* sinp = (const float*)d_in[2];
    const float* Wq   = (const float*)d_in[3];
    const float* Wk   = (const float*)d_in[4];
    const float* Wv   = (const float*)d_in[5];
    const float* Wo   = (const float*)d_in[6];
    const float* qw   = (const float*)d_in[7];
    const float* kw   = (const float*)d_in[8];
    float* out = (float*)d_out;

    char* ws = (char*)d_ws;
    size_t off = 0;
    auto carve = [&](size_t bytes) { char* p = ws + off; off += (bytes + 255) & ~(size_t)255; return p; };

    bf16* hsb  = (bf16*)carve((size_t)S_LEN * HIDDEN * 2);          // hidden bf16; reused as AO
    bf16* wqkv = (bf16*)carve((size_t)QKVW * HIDDEN * 2);           // fused [6144, 4096]
    bf16* wob  = (bf16*)carve((size_t)HIDDEN * NH * DH * 2);
    bf16* qkv  = (bf16*)carve((size_t)S_LEN * QKVW * 2);            // [S, 6144]
    bf16* vtb  = (bf16*)carve((size_t)NKV * DH * S_LEN * 2);

    // 1. all fp32->bf16 casts in one launch (12582912 float4 groups = 49152 blocks)
    cast_all<<<49152, 256, 0, stream>>>(hs, Wq, Wk, Wv, Wo,
                                        (unsigned short*)hsb, (unsigned short*)wqkv,
                                        (unsigned short*)wob);

    // 2. fused QKV projection (256^2 8-phase, 192 blocks, 2D XCD patch swizzle)
    gemm256<bf16><<<dim3(192), 512, 0, stream>>>(
        hsb, wqkv, qkv, S_LEN, QKVW, HIDDEN, HIDDEN / 64, 1);

    // 3. rmsnorm + rope in place on Q and K slices
    norm_rope<<<S_LEN * NH / 4, 256, 0, stream>>>(qkv, qw, cosp, sinp, 5, QKVW, 0);
    norm_rope<<<S_LEN * NKV / 4, 256, 0, stream>>>(qkv, kw, cosp, sinp, 3, QKVW, KOFF);

    // 4. V transpose
    transpose_v<<<dim3(NKV * DH / 32, S_LEN / 64), 256, 0, stream>>>(qkv, vtb, QKVW, VOFF);

    // 5. flash attention -> AO (reuse hsb); 1024 single-q-block blocks, heavy first
    bf16* aob = hsb;
    flash_attn<<<1024, 256, 0, stream>>>(qkv, vtb, aob);

    // 6. output projection: m97-style 128^2, grid 512 = 2 blocks/CU, no split-K
    gemm_lds<float><<<dim3(HIDDEN / 128, S_LEN / 128), 256, 0, stream>>>(
        aob, wob, out, S_LEN, HIDDEN, NH * DH);
}